// Round 1
// baseline (10314.206 us; speedup 1.0000x reference)
//
#include <hip/hip_runtime.h>
#include <math.h>

// Problem constants (fixed by the reference): B=4, N=4096, D=256
#define B_   4
#define N_   4096
#define D_   256
#define NWG  16      // workgroups per batch in the scan (column split)
#define DC   16      // columns per scan workgroup (256/16)

// ---------------------------------------------------------------------------
// Generic fp32 NT GEMM: C[m][n] = sum_k A[m][k]*W[n][k], 64x64 tile, 256 thr,
// 4x4 micro-tile. mode 0: plain store; mode 1: store sigmoid(acc);
// mode 2: A rows pre-scaled by rowscale[m], epilogue C = acc * C (gate mult).
// ---------------------------------------------------------------------------
__global__ __launch_bounds__(256)
void gemm_nt(const float* __restrict__ A, const float* __restrict__ W,
             float* __restrict__ C, const float* __restrict__ rowscale,
             int M, int Nn, int K, int mode)
{
    __shared__ __align__(16) float As[16][64];
    __shared__ __align__(16) float Ws[16][64];
    const int lt = threadIdx.x;
    const int m0 = blockIdx.x * 64;
    const int n0 = blockIdx.y * 64;
    const int lm = lt & 63;          // staging row within tile
    const int lk = (lt >> 6) << 2;   // staging k offset (0,4,8,12)
    const int tm = lt & 15;          // micro-tile row group
    const int tn = lt >> 4;          // micro-tile col group

    float rs = 1.0f;
    if (mode == 2) rs = rowscale[m0 + lm];

    float acc[4][4];
#pragma unroll
    for (int i = 0; i < 4; i++)
#pragma unroll
        for (int j = 0; j < 4; j++) acc[i][j] = 0.f;

    const float* Arow = A + (size_t)(m0 + lm) * K;
    const float* Wrow = W + (size_t)(n0 + lm) * K;

    for (int k0 = 0; k0 < K; k0 += 16) {
        float4 av = *(const float4*)(Arow + k0 + lk);
        float4 wv = *(const float4*)(Wrow + k0 + lk);
        if (mode == 2) { av.x *= rs; av.y *= rs; av.z *= rs; av.w *= rs; }
        __syncthreads();
        As[lk + 0][lm] = av.x; As[lk + 1][lm] = av.y;
        As[lk + 2][lm] = av.z; As[lk + 3][lm] = av.w;
        Ws[lk + 0][lm] = wv.x; Ws[lk + 1][lm] = wv.y;
        Ws[lk + 2][lm] = wv.z; Ws[lk + 3][lm] = wv.w;
        __syncthreads();
#pragma unroll
        for (int k = 0; k < 16; k++) {
            float4 a4 = *(const float4*)&As[k][tm << 2];
            float4 w4 = *(const float4*)&Ws[k][tn << 2];
            float aa[4] = {a4.x, a4.y, a4.z, a4.w};
            float ww[4] = {w4.x, w4.y, w4.z, w4.w};
#pragma unroll
            for (int i = 0; i < 4; i++)
#pragma unroll
                for (int j = 0; j < 4; j++)
                    acc[i][j] = fmaf(aa[i], ww[j], acc[i][j]);
        }
    }

#pragma unroll
    for (int i = 0; i < 4; i++) {
        const int m = m0 + (tm << 2) + i;
        float* crow = C + (size_t)m * Nn + n0 + (tn << 2);
#pragma unroll
        for (int j = 0; j < 4; j++) {
            float v = acc[i][j];
            if (mode == 1)      v = 1.0f / (1.0f + __expf(-v));
            else if (mode == 2) v = v * crow[j];
            crow[j] = v;
        }
    }
}

// ---------------------------------------------------------------------------
// Prep: causal depthwise conv(4) on q/k/v, RoPE + l2norm on q/k, eta/alpha
// gates from pg_w.  One block per (b,n) token, 256 threads = D.
// ---------------------------------------------------------------------------
__global__ __launch_bounds__(256)
void prep_kernel(const float* __restrict__ qkv, const float* __restrict__ x,
                 const float* __restrict__ qw, const float* __restrict__ qb2,
                 const float* __restrict__ kw, const float* __restrict__ kb2,
                 const float* __restrict__ vw, const float* __restrict__ vb2,
                 const float* __restrict__ fcos, const float* __restrict__ fsin,
                 const float* __restrict__ pgw, const float* __restrict__ pgb,
                 float* __restrict__ qn, float* __restrict__ kno,
                 float* __restrict__ vc, float* __restrict__ eta,
                 float* __restrict__ alpha)
{
    const int bn = blockIdx.x;
    const int b  = bn >> 12;        // N_=4096
    const int n  = bn & 4095;
    const int d  = threadIdx.x;

    float qc = qb2[d], kc = kb2[d], vcv = vb2[d];
#pragma unroll
    for (int j = 0; j < 4; j++) {
        const int nn = n - 3 + j;
        if (nn >= 0) {
            const float* r = qkv + ((size_t)(b << 12) + nn) * 768;
            qc  = fmaf(r[d],       qw[(d << 2) + j], qc);
            kc  = fmaf(r[256 + d], kw[(d << 2) + j], kc);
            vcv = fmaf(r[512 + d], vw[(d << 2) + j], vcv);
        }
    }

    __shared__ float sq[256], sk[256];
    sq[d] = qc; sk[d] = kc;
    const float xv = x[(size_t)bn * 256 + d];
    float p0 = xv * pgw[d];
    float p1 = xv * pgw[256 + d];
    __syncthreads();

    const int i2 = d >> 1;
    const float cs = fcos[((size_t)n << 7) + i2];
    const float sn = fsin[((size_t)n << 7) + i2];
    const float qe = sq[i2 << 1], qo = sq[(i2 << 1) + 1];
    const float ke = sk[i2 << 1], ko = sk[(i2 << 1) + 1];
    const float qr = (d & 1) ? fmaf(qe, sn, qo * cs) : fmaf(qe, cs, -qo * sn);
    const float kr = (d & 1) ? fmaf(ke, sn, ko * cs) : fmaf(ke, cs, -ko * sn);

    float r0 = qr * qr, r1 = kr * kr, r2 = p0, r3 = p1;
#pragma unroll
    for (int off = 32; off; off >>= 1) {
        r0 += __shfl_xor(r0, off, 64);
        r1 += __shfl_xor(r1, off, 64);
        r2 += __shfl_xor(r2, off, 64);
        r3 += __shfl_xor(r3, off, 64);
    }
    __shared__ float sred[4][4];
    const int w = d >> 6, lane = d & 63;
    if (lane == 0) { sred[0][w] = r0; sred[1][w] = r1; sred[2][w] = r2; sred[3][w] = r3; }
    __syncthreads();
    const float qs  = sred[0][0] + sred[0][1] + sred[0][2] + sred[0][3];
    const float ks2 = sred[1][0] + sred[1][1] + sred[1][2] + sred[1][3];
    const float qnm = fmaxf(sqrtf(qs),  1e-12f);
    const float knm = fmaxf(sqrtf(ks2), 1e-12f);
    const size_t o = (size_t)bn * 256 + d;
    qn[o]  = qr / qnm;
    kno[o] = kr / knm;
    vc[o]  = vcv;
    if (d == 0) {
        const float ps0 = sred[2][0] + sred[2][1] + sred[2][2] + sred[2][3] + pgb[0];
        const float ps1 = sred[3][0] + sred[3][1] + sred[3][2] + sred[3][3] + pgb[1];
        eta[bn]   = 1.f / (1.f + __expf(-ps0));
        alpha[bn] = 1.f / (1.f + __expf(-ps1));
    }
}

// ---------------------------------------------------------------------------
// Sequential scan. Grid = B_*NWG = 64 workgroups x 256 threads (co-resident).
// Each WG owns a 256-row x 16-col slab of its batch's A; thread = 4x4 tile.
// Per-step cross-WG coupling: one float atomicAdd (sum A^4) + release counter;
// consumer normalizes pred at the NEXT step, y normalization deferred to the
// output GEMM via s4sum.
// ---------------------------------------------------------------------------
__global__ __launch_bounds__(256, 1)
void scan_kernel(const float* __restrict__ qn, const float* __restrict__ kn,
                 const float* __restrict__ vc, const float* __restrict__ eta,
                 const float* __restrict__ alpha, const float* __restrict__ W0,
                 float* __restrict__ yraw, float* __restrict__ s4sum,
                 unsigned int* __restrict__ cnt)
{
    const int b       = blockIdx.x >> 4;   // / NWG
    const int wg      = blockIdx.x & 15;
    const int colbase = wg * DC;
    const int t    = threadIdx.x;
    const int rc   = t >> 2;               // 0..63 row-chunk
    const int cc   = t & 3;                // 0..3 col-chunk
    const int row0 = rc << 2;
    const int col0 = colbase + (cc << 2);
    const int lane = t & 63;
    const int wv   = t >> 6;

    __shared__ __align__(16) float g_s[DC];
    __shared__ float praw_s[DC];
    __shared__ float s4w_s[4];
    __shared__ float YT[16][65];   // [col][row-chunk], pad 65 to break bank aliasing
    __shared__ float PT[16][65];
    __shared__ float SB[32][9];

    const size_t bb = (size_t)b * N_;
    const float* kb_p  = kn  + bb * 256;
    const float* qb_p  = qn  + bb * 256;
    const float* vb_p  = vc  + bb * 256;
    const float* eta_p = eta + bb;
    const float* al_p  = alpha + bb;
    float*        s4_p = s4sum + bb;
    unsigned int* cnt_p = cnt + bb;
    float*        y_p  = yraw + bb * 256;

    float A[4][4];
#pragma unroll
    for (int i = 0; i < 4; i++)
#pragma unroll
        for (int j = 0; j < 4; j++) A[i][j] = 0.f;

    float4 kcur = *(const float4*)(kb_p + row0);        // k[0]
    float4 knx  = *(const float4*)(kb_p + 256 + row0);  // k[1]
    float4 qv   = *(const float4*)(qb_p + row0);        // q[0]
    float  et   = eta_p[0], al = al_p[0];
    float  vcol = (t < DC) ? vb_p[colbase + t] : 0.f;

    // praw init: pred_0 = k_0 @ W0 (no denom at t=0)
    {
        float pp0 = 0.f, pp1 = 0.f, pp2 = 0.f, pp3 = 0.f;
        const float* w0r = W0 + (size_t)row0 * 256 + col0;
        const float kk[4] = {kcur.x, kcur.y, kcur.z, kcur.w};
#pragma unroll
        for (int i = 0; i < 4; i++) {
            const float4 wr = *(const float4*)(w0r + i * 256);
            pp0 = fmaf(kk[i], wr.x, pp0);
            pp1 = fmaf(kk[i], wr.y, pp1);
            pp2 = fmaf(kk[i], wr.z, pp2);
            pp3 = fmaf(kk[i], wr.w, pp3);
        }
        const int c4 = cc << 2;
        PT[c4 + 0][rc] = pp0; PT[c4 + 1][rc] = pp1;
        PT[c4 + 2][rc] = pp2; PT[c4 + 3][rc] = pp3;
        __syncthreads();
        if (t < 128) {
            const int task = t >> 3, sub = t & 7;
            float s = 0.f;
#pragma unroll
            for (int r2 = 0; r2 < 8; r2++) s += PT[task][(sub << 3) + r2];
            SB[task][sub] = s;
        }
        __syncthreads();
        if (t < 16) {
            float s = 0.f;
#pragma unroll
            for (int j = 0; j < 8; j++) s += SB[t][j];
            praw_s[t] = s;   // read by same thread in g-phase: no barrier needed
        }
    }

    for (int tt = 0; tt < N_; ++tt) {
        // prefetch next step into registers (hidden under this step's work)
        const int tp = (tt + 1 < N_) ? tt + 1 : N_ - 1;
        const int tq = (tt + 2 < N_) ? tt + 2 : N_ - 1;
        const float4 qv_n  = *(const float4*)(qb_p + (size_t)tp * 256 + row0);
        const float4 knx_n = *(const float4*)(kb_p + (size_t)tq * 256 + row0);
        const float  et_n  = eta_p[tp], al_n = al_p[tp];
        const float  vcol_n = (t < DC) ? vb_p[(size_t)tp * 256 + colbase + t] : 0.f;

        // ---- g-phase (threads 0..15, one per owned column) ----
        if (t < DC) {
            float pr = praw_s[t];
            if (tt > 0) {
                const int idx = tt - 1;
                while (__hip_atomic_load(&cnt_p[idx], __ATOMIC_ACQUIRE,
                                         __HIP_MEMORY_SCOPE_AGENT) < NWG) { }
                const float s4 = __hip_atomic_load(&s4_p[idx], __ATOMIC_RELAXED,
                                                   __HIP_MEMORY_SCOPE_AGENT);
                pr = pr / (sqrtf(s4) + 1e-6f);
            }
            const float diff = pr - vcol;
            const float th = tanhf(10.f * diff);
            g_s[t] = 3.f * th * diff * diff;
        }
        __syncthreads();

        // ---- fused update pass: A update + sumA^4 + q^T A + k_next^T A ----
        const float4 g4 = *(const float4*)&g_s[cc << 2];
        const float c0 = et * g4.x, c1 = et * g4.y, c2 = et * g4.z, c3 = et * g4.w;
        const float kk[4]  = {kcur.x, kcur.y, kcur.z, kcur.w};
        const float qq[4]  = {qv.x, qv.y, qv.z, qv.w};
        const float kn4[4] = {knx.x, knx.y, knx.z, knx.w};
        float yp[4] = {0.f, 0.f, 0.f, 0.f};
        float pp[4] = {0.f, 0.f, 0.f, 0.f};
        float s4p = 0.f;
#pragma unroll
        for (int i = 0; i < 4; i++) {
            const float ki = kk[i];
            const float t0 = c0 * ki, t1 = c1 * ki, t2 = c2 * ki, t3 = c3 * ki;
            const float a0 = fmaf(al, A[i][0], -t0);
            const float a1 = fmaf(al, A[i][1], -t1);
            const float a2 = fmaf(al, A[i][2], -t2);
            const float a3 = fmaf(al, A[i][3], -t3);
            A[i][0] = a0; A[i][1] = a1; A[i][2] = a2; A[i][3] = a3;
            const float s0 = a0 * a0, s1 = a1 * a1, s2 = a2 * a2, s3 = a3 * a3;
            s4p = fmaf(s0, s0, s4p); s4p = fmaf(s1, s1, s4p);
            s4p = fmaf(s2, s2, s4p); s4p = fmaf(s3, s3, s4p);
            const float qi = qq[i], kni = kn4[i];
            yp[0] = fmaf(qi, a0, yp[0]); yp[1] = fmaf(qi, a1, yp[1]);
            yp[2] = fmaf(qi, a2, yp[2]); yp[3] = fmaf(qi, a3, yp[3]);
            pp[0] = fmaf(kni, a0, pp[0]); pp[1] = fmaf(kni, a1, pp[1]);
            pp[2] = fmaf(kni, a2, pp[2]); pp[3] = fmaf(kni, a3, pp[3]);
        }

        // s4: in-wave butterfly, then LDS combine across 4 waves
#pragma unroll
        for (int off = 32; off; off >>= 1) s4p += __shfl_xor(s4p, off, 64);
        if (lane == 0) s4w_s[wv] = s4p;

        // stage A: transposed partial write [col][rc]
        {
            const int c4 = cc << 2;
            YT[c4 + 0][rc] = yp[0]; YT[c4 + 1][rc] = yp[1];
            YT[c4 + 2][rc] = yp[2]; YT[c4 + 3][rc] = yp[3];
            PT[c4 + 0][rc] = pp[0]; PT[c4 + 1][rc] = pp[1];
            PT[c4 + 2][rc] = pp[2]; PT[c4 + 3][rc] = pp[3];
        }
        __syncthreads();

        // one atomic per WG: publish s4 contribution, then release counter
        if (t == 0) {
            const float s4tot = s4w_s[0] + s4w_s[1] + s4w_s[2] + s4w_s[3];
            __hip_atomic_fetch_add(&s4_p[tt], s4tot, __ATOMIC_RELAXED,
                                   __HIP_MEMORY_SCOPE_AGENT);
            __hip_atomic_fetch_add(&cnt_p[tt], 1u, __ATOMIC_RELEASE,
                                   __HIP_MEMORY_SCOPE_AGENT);
        }

        // stage B: 32 reductions (16 cols x {P,Y}) x 64 rc, 8 threads each.
        // Waves 0/1 -> PT, waves 2/3 -> YT (wave-uniform branch).
        {
            const int task = t >> 3, sub = t & 7;
            const int colx = task & 15;
            float s = 0.f;
            if (task < 16) {
#pragma unroll
                for (int r2 = 0; r2 < 8; r2++) s += PT[colx][(sub << 3) + r2];
            } else {
#pragma unroll
                for (int r2 = 0; r2 < 8; r2++) s += YT[colx][(sub << 3) + r2];
            }
            SB[task][sub] = s;
        }
        __syncthreads();

        // stage C: finalize praw (threads 0..15) and store yraw (16..31)
        if (t < 16) {
            float s = 0.f;
#pragma unroll
            for (int j = 0; j < 8; j++) s += SB[t][j];
            praw_s[t] = s;
        } else if (t < 32) {
            const int colx = t - 16;
            float s = 0.f;
#pragma unroll
            for (int j = 0; j < 8; j++) s += SB[16 + colx][j];
            y_p[(size_t)tt * 256 + colbase + colx] = s;
        }

        kcur = knx; knx = knx_n; qv = qv_n;
        et = et_n; al = al_n; vcol = vcol_n;
    }
}

// 1/(sqrt(s4sum)+EPS) per (b,t) row, consumed by the output GEMM as rowscale
__global__ void dscale_kernel(const float* __restrict__ s4sum,
                              float* __restrict__ dscale, int n)
{
    const int i = blockIdx.x * 256 + threadIdx.x;
    if (i < n) dscale[i] = 1.0f / (sqrtf(s4sum[i]) + 1e-6f);
}

// ---------------------------------------------------------------------------
extern "C" void kernel_launch(void* const* d_in, const int* in_sizes, int n_in,
                              void* d_out, int out_size, void* d_ws, size_t ws_size,
                              hipStream_t stream)
{
    (void)in_sizes; (void)n_in; (void)out_size; (void)ws_size;
    const float* x    = (const float*)d_in[0];
    const float* fcos = (const float*)d_in[1];
    const float* fsin = (const float*)d_in[2];
    const float* qkvw = (const float*)d_in[3];
    const float* qcw  = (const float*)d_in[4];
    const float* qcb  = (const float*)d_in[5];
    const float* kcw  = (const float*)d_in[6];
    const float* kcb  = (const float*)d_in[7];
    const float* vcw  = (const float*)d_in[8];
    const float* vcb  = (const float*)d_in[9];
    const float* pgw  = (const float*)d_in[10];
    const float* pgb  = (const float*)d_in[11];
    const float* W0   = (const float*)d_in[12];
    const float* gw   = (const float*)d_in[13];
    const float* ow   = (const float*)d_in[14];
    float* out = (float*)d_out;

    const int BN = B_ * N_;  // 16384
    float* ws = (float*)d_ws;
    // Workspace layout (~96.3 MiB). yraw overlays qkv (qkv dead after prep).
    float* qkv  = ws;                              // BN*768
    float* yraw = ws;                              // BN*256 (overlay)
    float* qn   = ws + (size_t)BN * 768;           // BN*256
    float* kn   = qn + (size_t)BN * 256;           // BN*256
    float* vc   = kn + (size_t)BN * 256;           // BN*256
    float* etaA = vc + (size_t)BN * 256;           // BN
    float* alA  = etaA + BN;                       // BN
    float* s4s  = alA + BN;                        // BN
    unsigned int* cntA = (unsigned int*)(s4s + BN);// BN
    float* dsc  = (float*)(cntA + BN);             // BN

    const dim3 blk(256);

    // 1) qkv projection: (BN x 768) = x (BN x 256) @ qkv_w^T
    gemm_nt<<<dim3(BN / 64, 768 / 64), blk, 0, stream>>>(
        x, qkvw, qkv, nullptr, BN, 768, 256, 0);

    // 2) conv + rope + l2norm + eta/alpha
    prep_kernel<<<BN, blk, 0, stream>>>(qkv, x, qcw, qcb, kcw, kcb, vcw, vcb,
                                        fcos, fsin, pgw, pgb,
                                        qn, kn, vc, etaA, alA);

    // 3) gate = sigmoid(x @ gate_w^T) -> stored in d_out (multiplied in step 7)
    gemm_nt<<<dim3(BN / 64, 256 / 64), blk, 0, stream>>>(
        x, gw, out, nullptr, BN, 256, 256, 1);

    // 4) zero the per-step reduction slots + arrival counters
    hipMemsetAsync(s4s, 0, (size_t)2 * BN * sizeof(float), stream);

    // 5) the sequential scan (64 persistent co-resident WGs)
    scan_kernel<<<B_ * NWG, blk, 0, stream>>>(qn, kn, vc, etaA, alA, W0,
                                              yraw, s4s, cntA);

    // 6) per-row y normalizer
    dscale_kernel<<<BN / 256, blk, 0, stream>>>(s4s, dsc, BN);

    // 7) out = (y*dscale) @ out_w^T * gate   (gate read+overwritten in d_out)
    gemm_nt<<<dim3(BN / 64, 256 / 64), blk, 0, stream>>>(
        yraw, ow, out, dsc, BN, 256, 256, 2);
}

// Round 2
// 6853.233 us; speedup vs baseline: 1.5050x; 1.5050x over previous
//
#include <hip/hip_runtime.h>
#include <math.h>

// Problem constants (fixed by the reference): B=4, N=4096, D=256
#define B_   4
#define N_   4096
#define D_   256
#define NWG  16      // workgroups per batch in the scan (column split)

// ---------------------------------------------------------------------------
// Generic fp32 NT GEMM: C[m][n] = sum_k A[m][k]*W[n][k], 64x64 tile, 256 thr,
// 4x4 micro-tile. mode 0: plain store; mode 1: store sigmoid(acc);
// mode 2: A rows pre-scaled by rowscale[m], epilogue C = acc * C (gate mult).
// ---------------------------------------------------------------------------
__global__ __launch_bounds__(256)
void gemm_nt(const float* __restrict__ A, const float* __restrict__ W,
             float* __restrict__ C, const float* __restrict__ rowscale,
             int M, int Nn, int K, int mode)
{
    __shared__ __align__(16) float As[16][64];
    __shared__ __align__(16) float Ws[16][64];
    const int lt = threadIdx.x;
    const int m0 = blockIdx.x * 64;
    const int n0 = blockIdx.y * 64;
    const int lm = lt & 63;          // staging row within tile
    const int lk = (lt >> 6) << 2;   // staging k offset (0,4,8,12)
    const int tm = lt & 15;          // micro-tile row group
    const int tn = lt >> 4;          // micro-tile col group

    float rs = 1.0f;
    if (mode == 2) rs = rowscale[m0 + lm];

    float acc[4][4];
#pragma unroll
    for (int i = 0; i < 4; i++)
#pragma unroll
        for (int j = 0; j < 4; j++) acc[i][j] = 0.f;

    const float* Arow = A + (size_t)(m0 + lm) * K;
    const float* Wrow = W + (size_t)(n0 + lm) * K;

    for (int k0 = 0; k0 < K; k0 += 16) {
        float4 av = *(const float4*)(Arow + k0 + lk);
        float4 wv = *(const float4*)(Wrow + k0 + lk);
        if (mode == 2) { av.x *= rs; av.y *= rs; av.z *= rs; av.w *= rs; }
        __syncthreads();
        As[lk + 0][lm] = av.x; As[lk + 1][lm] = av.y;
        As[lk + 2][lm] = av.z; As[lk + 3][lm] = av.w;
        Ws[lk + 0][lm] = wv.x; Ws[lk + 1][lm] = wv.y;
        Ws[lk + 2][lm] = wv.z; Ws[lk + 3][lm] = wv.w;
        __syncthreads();
#pragma unroll
        for (int k = 0; k < 16; k++) {
            float4 a4 = *(const float4*)&As[k][tm << 2];
            float4 w4 = *(const float4*)&Ws[k][tn << 2];
            float aa[4] = {a4.x, a4.y, a4.z, a4.w};
            float ww[4] = {w4.x, w4.y, w4.z, w4.w};
#pragma unroll
            for (int i = 0; i < 4; i++)
#pragma unroll
                for (int j = 0; j < 4; j++)
                    acc[i][j] = fmaf(aa[i], ww[j], acc[i][j]);
        }
    }

#pragma unroll
    for (int i = 0; i < 4; i++) {
        const int m = m0 + (tm << 2) + i;
        float* crow = C + (size_t)m * Nn + n0 + (tn << 2);
#pragma unroll
        for (int j = 0; j < 4; j++) {
            float v = acc[i][j];
            if (mode == 1)      v = 1.0f / (1.0f + __expf(-v));
            else if (mode == 2) v = v * crow[j];
            crow[j] = v;
        }
    }
}

// ---------------------------------------------------------------------------
// Prep: causal depthwise conv(4) on q/k/v, RoPE + l2norm on q/k, eta/alpha
// gates from pg_w.  One block per (b,n) token, 256 threads = D.
// ---------------------------------------------------------------------------
__global__ __launch_bounds__(256)
void prep_kernel(const float* __restrict__ qkv, const float* __restrict__ x,
                 const float* __restrict__ qw, const float* __restrict__ qb2,
                 const float* __restrict__ kw, const float* __restrict__ kb2,
                 const float* __restrict__ vw, const float* __restrict__ vb2,
                 const float* __restrict__ fcos, const float* __restrict__ fsin,
                 const float* __restrict__ pgw, const float* __restrict__ pgb,
                 float* __restrict__ qn, float* __restrict__ kno,
                 float* __restrict__ vc, float* __restrict__ eta,
                 float* __restrict__ alpha)
{
    const int bn = blockIdx.x;
    const int b  = bn >> 12;        // N_=4096
    const int n  = bn & 4095;
    const int d  = threadIdx.x;

    float qc = qb2[d], kc = kb2[d], vcv = vb2[d];
#pragma unroll
    for (int j = 0; j < 4; j++) {
        const int nn = n - 3 + j;
        if (nn >= 0) {
            const float* r = qkv + ((size_t)(b << 12) + nn) * 768;
            qc  = fmaf(r[d],       qw[(d << 2) + j], qc);
            kc  = fmaf(r[256 + d], kw[(d << 2) + j], kc);
            vcv = fmaf(r[512 + d], vw[(d << 2) + j], vcv);
        }
    }

    __shared__ float sq[256], sk[256];
    sq[d] = qc; sk[d] = kc;
    const float xv = x[(size_t)bn * 256 + d];
    float p0 = xv * pgw[d];
    float p1 = xv * pgw[256 + d];
    __syncthreads();

    const int i2 = d >> 1;
    const float cs = fcos[((size_t)n << 7) + i2];
    const float sn = fsin[((size_t)n << 7) + i2];
    const float qe = sq[i2 << 1], qo = sq[(i2 << 1) + 1];
    const float ke = sk[i2 << 1], ko = sk[(i2 << 1) + 1];
    const float qr = (d & 1) ? fmaf(qe, sn, qo * cs) : fmaf(qe, cs, -qo * sn);
    const float kr = (d & 1) ? fmaf(ke, sn, ko * cs) : fmaf(ke, cs, -ko * sn);

    float r0 = qr * qr, r1 = kr * kr, r2 = p0, r3 = p1;
#pragma unroll
    for (int off = 32; off; off >>= 1) {
        r0 += __shfl_xor(r0, off, 64);
        r1 += __shfl_xor(r1, off, 64);
        r2 += __shfl_xor(r2, off, 64);
        r3 += __shfl_xor(r3, off, 64);
    }
    __shared__ float sred[4][4];
    const int w = d >> 6, lane = d & 63;
    if (lane == 0) { sred[0][w] = r0; sred[1][w] = r1; sred[2][w] = r2; sred[3][w] = r3; }
    __syncthreads();
    const float qs  = sred[0][0] + sred[0][1] + sred[0][2] + sred[0][3];
    const float ks2 = sred[1][0] + sred[1][1] + sred[1][2] + sred[1][3];
    const float qnm = fmaxf(sqrtf(qs),  1e-12f);
    const float knm = fmaxf(sqrtf(ks2), 1e-12f);
    const size_t o = (size_t)bn * 256 + d;
    qn[o]  = qr / qnm;
    kno[o] = kr / knm;
    vc[o]  = vcv;
    if (d == 0) {
        const float ps0 = sred[2][0] + sred[2][1] + sred[2][2] + sred[2][3] + pgb[0];
        const float ps1 = sred[3][0] + sred[3][1] + sred[3][2] + sred[3][3] + pgb[1];
        eta[bn]   = 1.f / (1.f + __expf(-ps0));
        alpha[bn] = 1.f / (1.f + __expf(-ps1));
    }
}

// ---------------------------------------------------------------------------
// Scan v2: 64 WGs x 256 thr.  Wave = 4-column strip (256 rows x 4 cols);
// lane = row chunk (4 rows).  Zero __syncthreads in the loop; zero LDS.
// Cross-wave coupling (the scalar sum A^4) via 64 tagged 8-byte slots per
// (batch, step): each wave publishes {tag=tt+1, s4partial} with one relaxed
// atomic store; consumers gather all 64 slots in one coalesced wave load,
// ballot-check tags, butterfly-sum payloads.  The publish happens right
// after the A-update; the y/praw matvecs run while the message is in flight.
// ---------------------------------------------------------------------------
__device__ __forceinline__ float wave_sum(float v)
{
#pragma unroll
    for (int off = 1; off < 64; off <<= 1) v += __shfl_xor(v, off, 64);
    return v;
}

__global__ __launch_bounds__(256, 1)
void scan_kernel(const float* __restrict__ qn, const float* __restrict__ kn,
                 const float* __restrict__ vc, const float* __restrict__ eta,
                 const float* __restrict__ alpha, const float* __restrict__ W0,
                 float* __restrict__ yraw, float* __restrict__ dsc,
                 unsigned long long* __restrict__ slots)
{
    const int b    = blockIdx.x >> 4;
    const int wg   = blockIdx.x & 15;
    const int t    = threadIdx.x;
    const int cc   = t >> 6;            // wave id = column chunk (0..3)
    const int lane = t & 63;            // row chunk
    const int row0 = lane << 2;
    const int col0 = wg * 16 + (cc << 2);
    const int l2   = lane & 3;          // which of my wave's 4 cols this lane "owns"

    const size_t bb = (size_t)b * N_;
    const float* kb_p  = kn  + bb * 256;
    const float* qb_p  = qn  + bb * 256;
    const float* vb_p  = vc  + bb * 256;
    const float* eta_p = eta + bb;
    const float* al_p  = alpha + bb;
    float*       y_p   = yraw + bb * 256;
    unsigned long long* slot_b = slots + bb * 64;   // 64 producer slots per (b,t)
    const int myslot = (wg << 2) + cc;

    float A[4][4];
#pragma unroll
    for (int i = 0; i < 4; i++)
#pragma unroll
        for (int j = 0; j < 4; j++) A[i][j] = 0.f;

    float4 kcur = *(const float4*)(kb_p + row0);
    float4 knx  = *(const float4*)(kb_p + 256 + row0);
    float4 qv   = *(const float4*)(qb_p + row0);
    float  et   = eta_p[0], al = al_p[0];
    float  vsel = vb_p[col0 + l2];

    // praw_0 = k_0 @ W0 for our 4 columns (replicated across lanes)
    float pr0, pr1, pr2, pr3;
    {
        float p0 = 0.f, p1 = 0.f, p2 = 0.f, p3 = 0.f;
        const float* w0r = W0 + (size_t)row0 * 256 + col0;
        const float kk[4] = {kcur.x, kcur.y, kcur.z, kcur.w};
#pragma unroll
        for (int i = 0; i < 4; i++) {
            const float4 wr = *(const float4*)(w0r + (size_t)i * 256);
            p0 = fmaf(kk[i], wr.x, p0);
            p1 = fmaf(kk[i], wr.y, p1);
            p2 = fmaf(kk[i], wr.z, p2);
            p3 = fmaf(kk[i], wr.w, p3);
        }
        pr0 = wave_sum(p0); pr1 = wave_sum(p1);
        pr2 = wave_sum(p2); pr3 = wave_sum(p3);
    }

    for (int tt = 0; tt < N_; ++tt) {
        // prefetch next step (consumed at the bottom / next iteration)
        const int tp = (tt + 1 < N_) ? tt + 1 : N_ - 1;
        const int tq = (tt + 2 < N_) ? tt + 2 : N_ - 1;
        const float4 qv_n   = *(const float4*)(qb_p + (size_t)tp * 256 + row0);
        const float4 knx_n  = *(const float4*)(kb_p + (size_t)tq * 256 + row0);
        const float  et_n   = eta_p[tp], al_n = al_p[tp];
        const float  vsel_n = vb_p[(size_t)tp * 256 + col0 + l2];

        // ---- denom for this step (sum A_{tt-1}^4 across the batch) ----
        float prx = pr0;
        prx = (l2 == 1) ? pr1 : prx;
        prx = (l2 == 2) ? pr2 : prx;
        prx = (l2 == 3) ? pr3 : prx;
        if (tt > 0) {
            unsigned long long* sp = slot_b + (size_t)(tt - 1) * 64 + lane;
            unsigned long long pk;
            do {
                pk = __hip_atomic_load(sp, __ATOMIC_RELAXED, __HIP_MEMORY_SCOPE_AGENT);
            } while (__ballot((unsigned int)(pk >> 32) != (unsigned int)tt));
            const float s4 = wave_sum(__uint_as_float((unsigned int)pk));
            const float denom = sqrtf(s4) + 1e-6f;
            prx = prx / denom;
            if (wg == 0 && cc == 0 && lane == 0) dsc[bb + tt - 1] = 1.0f / denom;
        }

        // ---- g for this lane's column, broadcast within each 4-lane group ----
        const float diff = prx - vsel;
        const float e  = __expf(20.0f * diff);          // tanh(10d) = 1 - 2/(e+1)
        const float th = 1.0f - 2.0f / (e + 1.0f);
        const float gv = 3.0f * th * diff * diff;
        const float g0 = __shfl(gv, 0, 4);
        const float g1 = __shfl(gv, 1, 4);
        const float g2 = __shfl(gv, 2, 4);
        const float g3 = __shfl(gv, 3, 4);

        // ---- A update + sum A^4 partial ----
        const float c0 = et * g0, c1 = et * g1, c2 = et * g2, c3 = et * g3;
        const float kk[4] = {kcur.x, kcur.y, kcur.z, kcur.w};
        float s4p = 0.f;
#pragma unroll
        for (int i = 0; i < 4; i++) {
            const float ki = kk[i];
            const float a0 = fmaf(al, A[i][0], -(c0 * ki));
            const float a1 = fmaf(al, A[i][1], -(c1 * ki));
            const float a2 = fmaf(al, A[i][2], -(c2 * ki));
            const float a3 = fmaf(al, A[i][3], -(c3 * ki));
            A[i][0] = a0; A[i][1] = a1; A[i][2] = a2; A[i][3] = a3;
            const float s0 = a0 * a0, s1 = a1 * a1, s2 = a2 * a2, s3 = a3 * a3;
            s4p = fmaf(s0, s0, s4p); s4p = fmaf(s1, s1, s4p);
            s4p = fmaf(s2, s2, s4p); s4p = fmaf(s3, s3, s4p);
        }
        s4p = wave_sum(s4p);

        // ---- publish ASAP (matvecs below hide the flight time) ----
        if (lane == 0) {
            const unsigned long long pk =
                ((unsigned long long)(unsigned int)(tt + 1) << 32) |
                (unsigned long long)__float_as_uint(s4p);
            __hip_atomic_store(slot_b + (size_t)tt * 64 + myslot, pk,
                               __ATOMIC_RELAXED, __HIP_MEMORY_SCOPE_AGENT);
        }

        // ---- y_t = q_t . A (raw) and praw_{t+1} = k_{t+1} . A ----
        const float qq[4]  = {qv.x, qv.y, qv.z, qv.w};
        const float kn4[4] = {knx.x, knx.y, knx.z, knx.w};
        float y0 = 0.f, y1 = 0.f, y2 = 0.f, y3 = 0.f;
        float p0 = 0.f, p1 = 0.f, p2 = 0.f, p3 = 0.f;
#pragma unroll
        for (int i = 0; i < 4; i++) {
            const float qi = qq[i], kni = kn4[i];
            y0 = fmaf(qi, A[i][0], y0); y1 = fmaf(qi, A[i][1], y1);
            y2 = fmaf(qi, A[i][2], y2); y3 = fmaf(qi, A[i][3], y3);
            p0 = fmaf(kni, A[i][0], p0); p1 = fmaf(kni, A[i][1], p1);
            p2 = fmaf(kni, A[i][2], p2); p3 = fmaf(kni, A[i][3], p3);
        }
        y0 = wave_sum(y0); y1 = wave_sum(y1);
        y2 = wave_sum(y2); y3 = wave_sum(y3);
        pr0 = wave_sum(p0); pr1 = wave_sum(p1);
        pr2 = wave_sum(p2); pr3 = wave_sum(p3);

        if (lane == 0)
            *(float4*)(y_p + (size_t)tt * 256 + col0) = make_float4(y0, y1, y2, y3);

        kcur = knx; knx = knx_n; qv = qv_n;
        et = et_n; al = al_n; vsel = vsel_n;
    }

    // final step's denom -> dsc[N-1] (one wave per batch)
    if (wg == 0 && cc == 0) {
        unsigned long long* sp = slot_b + (size_t)(N_ - 1) * 64 + lane;
        unsigned long long pk;
        do {
            pk = __hip_atomic_load(sp, __ATOMIC_RELAXED, __HIP_MEMORY_SCOPE_AGENT);
        } while (__ballot((unsigned int)(pk >> 32) != (unsigned int)N_));
        const float s4 = wave_sum(__uint_as_float((unsigned int)pk));
        if (lane == 0) dsc[bb + N_ - 1] = 1.0f / (sqrtf(s4) + 1e-6f);
    }
}

// ---------------------------------------------------------------------------
extern "C" void kernel_launch(void* const* d_in, const int* in_sizes, int n_in,
                              void* d_out, int out_size, void* d_ws, size_t ws_size,
                              hipStream_t stream)
{
    (void)in_sizes; (void)n_in; (void)out_size; (void)ws_size;
    const float* x    = (const float*)d_in[0];
    const float* fcos = (const float*)d_in[1];
    const float* fsin = (const float*)d_in[2];
    const float* qkvw = (const float*)d_in[3];
    const float* qcw  = (const float*)d_in[4];
    const float* qcb  = (const float*)d_in[5];
    const float* kcw  = (const float*)d_in[6];
    const float* kcb  = (const float*)d_in[7];
    const float* vcw  = (const float*)d_in[8];
    const float* vcb  = (const float*)d_in[9];
    const float* pgw  = (const float*)d_in[10];
    const float* pgb  = (const float*)d_in[11];
    const float* W0   = (const float*)d_in[12];
    const float* gw   = (const float*)d_in[13];
    const float* ow   = (const float*)d_in[14];
    float* out = (float*)d_out;

    const int BN = B_ * N_;  // 16384
    float* ws = (float*)d_ws;
    // Workspace layout (~96.5 MiB):
    //   [0, BN*768)           qkv   (dead after prep)
    //     [0, BN*256)           yraw  (overlay)
    //     [BN*256, BN*384)      slots (overlay, BN*64 x u64)  -- tag check is
    //                           poison/garbage-safe: tags are 1..4096, stale
    //                           float upper-words are 0 or >= 0x00800000.
    float* qkv  = ws;
    float* yraw = ws;
    unsigned long long* slots = (unsigned long long*)(ws + (size_t)BN * 256);
    float* qn   = ws + (size_t)BN * 768;
    float* kn   = qn + (size_t)BN * 256;
    float* vc   = kn + (size_t)BN * 256;
    float* etaA = vc + (size_t)BN * 256;
    float* alA  = etaA + BN;
    float* dsc  = alA + BN;

    const dim3 blk(256);

    // 1) qkv projection: (BN x 768) = x (BN x 256) @ qkv_w^T
    gemm_nt<<<dim3(BN / 64, 768 / 64), blk, 0, stream>>>(
        x, qkvw, qkv, nullptr, BN, 768, 256, 0);

    // 2) conv + rope + l2norm + eta/alpha
    prep_kernel<<<BN, blk, 0, stream>>>(qkv, x, qcw, qcb, kcw, kcb, vcw, vcb,
                                        fcos, fsin, pgw, pgb,
                                        qn, kn, vc, etaA, alA);

    // 3) gate = sigmoid(x @ gate_w^T) -> stored in d_out (multiplied in step 5)
    gemm_nt<<<dim3(BN / 64, 256 / 64), blk, 0, stream>>>(
        x, gw, out, nullptr, BN, 256, 256, 1);

    // 4) the sequential scan (64 co-resident WGs; writes yraw + dsc)
    scan_kernel<<<B_ * NWG, blk, 0, stream>>>(qn, kn, vc, etaA, alA, W0,
                                              yraw, dsc, slots);

    // 5) out = (y*dscale) @ out_w^T * gate   (gate read+overwritten in d_out)
    gemm_nt<<<dim3(BN / 64, 256 / 64), blk, 0, stream>>>(
        yraw, ow, out, dsc, BN, 256, 256, 2);
}